// Round 9
// baseline (11.313 us; speedup 1.0000x reference)
//
#include <hip/hip_runtime.h>

#define PROTON_F 1.00782503207f
#define WATER_F 18.0105646863f
#define HUBER_DELTA_F 0.2f

constexpr int B = 512;
constexpr int L = 64;
constexpr int V = 28;
constexpr int M = 1024;
constexpr int THREADS = 512;      // 8 waves/block, 2 blocks/CU -> 16 waves/CU

// Two-kernel structure (fused single-kernel proven slower in R6/R7: per-block
// cross-XCD publication costs more than a second dispatch).
// Kernel1: one block per batch row b. Theoretical peaks are two SORTED arrays
// (b_ions ascend, y_ions stored reversed); min|T-m| via 6-step branchless
// lower-bound binary search. 2 observed peaks per thread.

__global__ __launch_bounds__(THREADS)
void spectrum_loss_main(const float* __restrict__ probs,       // [B, L, V]
                        const float* __restrict__ obs_mass,    // [B, M]
                        const float* __restrict__ obs_int,     // [B, M]
                        const int* __restrict__ mask,          // [B, M] (bool->int32)
                        const float* __restrict__ aa,          // [V]
                        float* __restrict__ per_b)             // [B]
{
    const int b = blockIdx.x;
    const int tid = threadIdx.x;
    const int lane = tid & 63;
    const int wave = tid >> 6;

    __shared__ float s_bA[64];           // ascending b_ions + inf sentinel
    __shared__ float s_yA[64];           // ascending (reversed) y_ions + inf
    __shared__ float s_red[16];

    // ---- issue observed-peak loads FIRST: HBM latency hides under dot phase
    const size_t obase = (size_t)b * M;
    const float2 om2 = ((const float2*)(obs_mass + obase))[tid];
    const float2 oi2 = ((const float2*)(obs_int + obase))[tid];
    const int2   mk2 = ((const int2*)(mask + obase))[tid];

    // ---- wave 0: dot from global, Kogge-Stone cumsum, sorted peak arrays
    if (wave == 0) {
        const float* prow = probs + (size_t)b * (L * V) + lane * V;  // 112B-aligned
        float r = 0.f;
        #pragma unroll
        for (int c = 0; c < 7; ++c) {
            const float4 p = ((const float4*)prow)[c];
            const float4 a = ((const float4*)aa)[c];
            r += p.x * a.x + p.y * a.y + p.z * a.z + p.w * a.w;
        }
        float pref = r;
        #pragma unroll
        for (int off = 1; off < 64; off <<= 1) {
            const float t = __shfl_up(pref, off, 64);
            if (lane >= off) pref += t;
        }
        const float total = __shfl(pref, 63, 64);
        s_bA[lane] = (lane < 63) ? pref + PROTON_F : 1e30f;
        if (lane < 63) s_yA[62 - lane] = total - pref + WATER_F + PROTON_F;
        else           s_yA[63] = 1e30f;
    }
    __syncthreads();

    // ---- branchless lower-bound binary search, 2 obs peaks x 2 arrays
    const float omv0 = om2.x, omv1 = om2.y;
    int ib0 = 0, ib1 = 0, iy0 = 0, iy1 = 0;
    #pragma unroll
    for (int k = 32; k >= 1; k >>= 1) {
        ib0 += (s_bA[ib0 + k - 1] < omv0) ? k : 0;
        ib1 += (s_bA[ib1 + k - 1] < omv1) ? k : 0;
        iy0 += (s_yA[iy0 + k - 1] < omv0) ? k : 0;
        iy1 += (s_yA[iy1 + k - 1] < omv1) ? k : 0;
    }
    float mind0, mind1;
    {
        float db, dy;
        db = fminf(fabsf(s_bA[ib0] - omv0), fabsf(s_bA[ib0 - (ib0 > 0)] - omv0));
        dy = fminf(fabsf(s_yA[iy0] - omv0), fabsf(s_yA[iy0 - (iy0 > 0)] - omv0));
        mind0 = fminf(db, dy);
        db = fminf(fabsf(s_bA[ib1] - omv1), fabsf(s_bA[ib1 - (ib1 > 0)] - omv1));
        dy = fminf(fabsf(s_yA[iy1] - omv1), fabsf(s_yA[iy1 - (iy1 > 0)] - omv1));
        mind1 = fminf(db, dy);
    }

    // ---- huber, weight, per-thread partial sums
    float wsum = 0.f, isum = 0.f;
    {
        float d, h;
        d = mind0; h = (d <= HUBER_DELTA_F) ? 0.5f * d * d
                                            : HUBER_DELTA_F * (d - 0.5f * HUBER_DELTA_F);
        wsum += h * oi2.x * (float)mk2.x;  isum += oi2.x;
        d = mind1; h = (d <= HUBER_DELTA_F) ? 0.5f * d * d
                                            : HUBER_DELTA_F * (d - 0.5f * HUBER_DELTA_F);
        wsum += h * oi2.y * (float)mk2.y;  isum += oi2.y;
    }

    // ---- wave shuffle reduction, then 8 wave-sums via LDS (single barrier)
    #pragma unroll
    for (int off = 32; off > 0; off >>= 1) {
        wsum += __shfl_down(wsum, off, 64);
        isum += __shfl_down(isum, off, 64);
    }
    if (lane == 0) { s_red[wave] = wsum; s_red[8 + wave] = isum; }
    __syncthreads();

    if (tid == 0) {
        const float w = (s_red[0] + s_red[1]) + (s_red[2] + s_red[3])
                      + (s_red[4] + s_red[5]) + (s_red[6] + s_red[7]);
        const float i = (s_red[8] + s_red[9]) + (s_red[10] + s_red[11])
                      + (s_red[12] + s_red[13]) + (s_red[14] + s_red[15]);
        per_b[b] = w / fmaxf(i, 1e-8f);
    }
}

// Single wave: 64 threads x 8 values, pure shuffle reduce, no LDS, no barriers.
__global__ __launch_bounds__(64)
void final_reduce_wave(const float* __restrict__ per_b, float* __restrict__ out)
{
    const int lane = threadIdx.x;
    const float4 a = ((const float4*)per_b)[lane * 2];
    const float4 c = ((const float4*)per_b)[lane * 2 + 1];
    float v = (a.x + a.y) + (a.z + a.w) + (c.x + c.y) + (c.z + c.w);
    #pragma unroll
    for (int off = 32; off > 0; off >>= 1)
        v += __shfl_down(v, off, 64);
    if (lane == 0) out[0] = v * (1.0f / (float)B);
}

extern "C" void kernel_launch(void* const* d_in, const int* in_sizes, int n_in,
                              void* d_out, int out_size, void* d_ws, size_t ws_size,
                              hipStream_t stream)
{
    const float* probs = (const float*)d_in[0];
    const float* omass = (const float*)d_in[1];
    const float* oint  = (const float*)d_in[2];
    const int*   pmask = (const int*)d_in[3];
    const float* aa    = (const float*)d_in[4];
    float* out  = (float*)d_out;
    float* perb = (float*)d_ws;  // 512 floats, fully rewritten each call

    spectrum_loss_main<<<B, THREADS, 0, stream>>>(probs, omass, oint, pmask, aa, perb);
    final_reduce_wave<<<1, 64, 0, stream>>>(perb, out);
}

// Round 10
// 11.285 us; speedup vs baseline: 1.0024x; 1.0024x over previous
//
#include <hip/hip_runtime.h>

#define PROTON_F 1.00782503207f
#define WATER_F 18.0105646863f
#define HUBER_DELTA_F 0.2f

constexpr int B = 512;
constexpr int L = 64;
constexpr int V = 28;
constexpr int M = 1024;
constexpr int THREADS = 512;      // 8 waves/block, 2 blocks/CU -> 16 waves/CU

// Two-kernel structure (fused single-kernel proven slower in R6/R7: per-block
// cross-XCD publication costs more than a second dispatch).
// Kernel1: one block per batch row b. Theoretical peaks are two SORTED arrays
// (b_ions ascend, y_ions stored reversed); min|T-m| via 6-step branchless
// lower-bound binary search. 2 observed peaks per thread.

__global__ __launch_bounds__(THREADS)
void spectrum_loss_main(const float* __restrict__ probs,       // [B, L, V]
                        const float* __restrict__ obs_mass,    // [B, M]
                        const float* __restrict__ obs_int,     // [B, M]
                        const int* __restrict__ mask,          // [B, M] (bool->int32)
                        const float* __restrict__ aa,          // [V]
                        float* __restrict__ per_b)             // [B]
{
    const int b = blockIdx.x;
    const int tid = threadIdx.x;
    const int lane = tid & 63;
    const int wave = tid >> 6;

    __shared__ float s_bA[64];           // ascending b_ions + inf sentinel
    __shared__ float s_yA[64];           // ascending (reversed) y_ions + inf
    __shared__ float s_red[16];

    // ---- issue observed-peak loads FIRST: HBM latency hides under dot phase
    const size_t obase = (size_t)b * M;
    const float2 om2 = ((const float2*)(obs_mass + obase))[tid];
    const float2 oi2 = ((const float2*)(obs_int + obase))[tid];
    const int2   mk2 = ((const int2*)(mask + obase))[tid];

    // ---- wave 0: dot from global, Kogge-Stone cumsum, sorted peak arrays
    if (wave == 0) {
        const float* prow = probs + (size_t)b * (L * V) + lane * V;  // 112B-aligned
        float r = 0.f;
        #pragma unroll
        for (int c = 0; c < 7; ++c) {
            const float4 p = ((const float4*)prow)[c];
            const float4 a = ((const float4*)aa)[c];
            r += p.x * a.x + p.y * a.y + p.z * a.z + p.w * a.w;
        }
        float pref = r;
        #pragma unroll
        for (int off = 1; off < 64; off <<= 1) {
            const float t = __shfl_up(pref, off, 64);
            if (lane >= off) pref += t;
        }
        const float total = __shfl(pref, 63, 64);
        s_bA[lane] = (lane < 63) ? pref + PROTON_F : 1e30f;
        if (lane < 63) s_yA[62 - lane] = total - pref + WATER_F + PROTON_F;
        else           s_yA[63] = 1e30f;
    }
    __syncthreads();

    // ---- branchless lower-bound binary search, 2 obs peaks x 2 arrays
    const float omv0 = om2.x, omv1 = om2.y;
    int ib0 = 0, ib1 = 0, iy0 = 0, iy1 = 0;
    #pragma unroll
    for (int k = 32; k >= 1; k >>= 1) {
        ib0 += (s_bA[ib0 + k - 1] < omv0) ? k : 0;
        ib1 += (s_bA[ib1 + k - 1] < omv1) ? k : 0;
        iy0 += (s_yA[iy0 + k - 1] < omv0) ? k : 0;
        iy1 += (s_yA[iy1 + k - 1] < omv1) ? k : 0;
    }
    float mind0, mind1;
    {
        float db, dy;
        db = fminf(fabsf(s_bA[ib0] - omv0), fabsf(s_bA[ib0 - (ib0 > 0)] - omv0));
        dy = fminf(fabsf(s_yA[iy0] - omv0), fabsf(s_yA[iy0 - (iy0 > 0)] - omv0));
        mind0 = fminf(db, dy);
        db = fminf(fabsf(s_bA[ib1] - omv1), fabsf(s_bA[ib1 - (ib1 > 0)] - omv1));
        dy = fminf(fabsf(s_yA[iy1] - omv1), fabsf(s_yA[iy1 - (iy1 > 0)] - omv1));
        mind1 = fminf(db, dy);
    }

    // ---- huber, weight, per-thread partial sums
    float wsum = 0.f, isum = 0.f;
    {
        float d, h;
        d = mind0; h = (d <= HUBER_DELTA_F) ? 0.5f * d * d
                                            : HUBER_DELTA_F * (d - 0.5f * HUBER_DELTA_F);
        wsum += h * oi2.x * (float)mk2.x;  isum += oi2.x;
        d = mind1; h = (d <= HUBER_DELTA_F) ? 0.5f * d * d
                                            : HUBER_DELTA_F * (d - 0.5f * HUBER_DELTA_F);
        wsum += h * oi2.y * (float)mk2.y;  isum += oi2.y;
    }

    // ---- wave shuffle reduction, then 8 wave-sums via LDS (single barrier)
    #pragma unroll
    for (int off = 32; off > 0; off >>= 1) {
        wsum += __shfl_down(wsum, off, 64);
        isum += __shfl_down(isum, off, 64);
    }
    if (lane == 0) { s_red[wave] = wsum; s_red[8 + wave] = isum; }
    __syncthreads();

    if (tid == 0) {
        const float w = (s_red[0] + s_red[1]) + (s_red[2] + s_red[3])
                      + (s_red[4] + s_red[5]) + (s_red[6] + s_red[7]);
        const float i = (s_red[8] + s_red[9]) + (s_red[10] + s_red[11])
                      + (s_red[12] + s_red[13]) + (s_red[14] + s_red[15]);
        per_b[b] = w / fmaxf(i, 1e-8f);
    }
}

// Single wave: 64 threads x 8 values, pure shuffle reduce, no LDS, no barriers.
__global__ __launch_bounds__(64)
void final_reduce_wave(const float* __restrict__ per_b, float* __restrict__ out)
{
    const int lane = threadIdx.x;
    const float4 a = ((const float4*)per_b)[lane * 2];
    const float4 c = ((const float4*)per_b)[lane * 2 + 1];
    float v = (a.x + a.y) + (a.z + a.w) + (c.x + c.y) + (c.z + c.w);
    #pragma unroll
    for (int off = 32; off > 0; off >>= 1)
        v += __shfl_down(v, off, 64);
    if (lane == 0) out[0] = v * (1.0f / (float)B);
}

extern "C" void kernel_launch(void* const* d_in, const int* in_sizes, int n_in,
                              void* d_out, int out_size, void* d_ws, size_t ws_size,
                              hipStream_t stream)
{
    const float* probs = (const float*)d_in[0];
    const float* omass = (const float*)d_in[1];
    const float* oint  = (const float*)d_in[2];
    const int*   pmask = (const int*)d_in[3];
    const float* aa    = (const float*)d_in[4];
    float* out  = (float*)d_out;
    float* perb = (float*)d_ws;  // 512 floats, fully rewritten each call

    spectrum_loss_main<<<B, THREADS, 0, stream>>>(probs, omass, oint, pmask, aa, perb);
    final_reduce_wave<<<1, 64, 0, stream>>>(perb, out);
}